// Round 1
// baseline (993.324 us; speedup 1.0000x reference)
//
#include <hip/hip_runtime.h>
#include <stdint.h>

#define NTH 256
#define ROWN 2048

// Monotonic float->uint transform: order-preserving for all finite floats.
__device__ __forceinline__ uint32_t f2u(float f) {
    uint32_t b = __float_as_uint(f);
    return (b & 0x80000000u) ? ~b : (b | 0x80000000u);
}
__device__ __forceinline__ float u2f(uint32_t u) {
    uint32_t b = (u & 0x80000000u) ? (u & 0x7fffffffu) : ~u;
    return __uint_as_float(b);
}

__global__ __launch_bounds__(NTH) void topk_softmax_kernel(
    const float* __restrict__ in, float* __restrict__ out)
{
    __shared__ uint32_t su[ROWN];     // row values (sortable uint) by index
    __shared__ uint32_t hist[256];    // radix histogram
    __shared__ uint32_t swred[4];     // cross-wave uint reduce
    __shared__ float    sfred[4];     // cross-wave float reduce
    __shared__ uint32_t s_sel[2];     // broadcast: selected digit, new rk

    const int tid  = threadIdx.x;
    const int lane = tid & 63;
    const int wid  = tid >> 6;
    const int row  = blockIdx.x;
    const int h    = (row >> 11) & 3;           // rows per (b,h) slab = N = 2048
    const int klist[4] = {10, 20, 40, 500};
    const uint32_t k = (uint32_t)klist[h];

    const float4* src4 = (const float4*)(in  + (size_t)row * ROWN);
    float4*       dst4 = (float4*)      (out + (size_t)row * ROWN);

    // ---- load 8 elements/thread, coalesced float4 ----
    float4 a0 = src4[tid];
    float4 a1 = src4[tid + NTH];
    float v[8] = {a0.x, a0.y, a0.z, a0.w, a1.x, a1.y, a1.z, a1.w};
    uint32_t u[8];
    uint32_t umax = 0;
#pragma unroll
    for (int j = 0; j < 8; ++j) {
        u[j] = f2u(v[j]);
        umax = (u[j] > umax) ? u[j] : umax;
    }
    const int base0 = 4 * tid;
    const int base1 = 4 * tid + 4 * NTH;
#pragma unroll
    for (int j = 0; j < 4; ++j) {
        su[base0 + j] = u[j];
        su[base1 + j] = u[4 + j];
    }

    // ---- block max (= row max; top-1 always kept) ----
#pragma unroll
    for (int d = 32; d > 0; d >>= 1) {
        uint32_t t = (uint32_t)__shfl_xor((int)umax, d);
        umax = (t > umax) ? t : umax;
    }
    if (lane == 0) swred[wid] = umax;
    __syncthreads();
    {
        uint32_t m01 = (swred[0] > swred[1]) ? swred[0] : swred[1];
        uint32_t m23 = (swred[2] > swred[3]) ? swred[2] : swred[3];
        umax = (m01 > m23) ? m01 : m23;
    }
    const float M = u2f(umax);

    // exps cached in registers (v dead after this)
    float e[8];
#pragma unroll
    for (int j = 0; j < 8; ++j) e[j] = __expf(v[j] - M);

    // ---- 4-pass radix select for the k-th largest uint ----
    uint32_t rk = k;          // how many elements matching current prefix still needed
    uint32_t prefix = 0;
    uint32_t cand = 0xFFu;    // bitmask: element j still a candidate
#pragma unroll
    for (int pass = 0; pass < 4; ++pass) {
        const int shift = 24 - 8 * pass;
        hist[tid] = 0;
        __syncthreads();                                   // S1
#pragma unroll
        for (int j = 0; j < 8; ++j)
            if (cand & (1u << j))
                atomicAdd(&hist[(u[j] >> shift) & 255u], 1u);
        __syncthreads();                                   // S2
        // descending suffix count: thread t owns bin b = 255-t
        const uint32_t b = 255u - (uint32_t)tid;
        const uint32_t x = hist[b];
        uint32_t sc = x;
#pragma unroll
        for (int d = 1; d < 64; d <<= 1) {
            uint32_t t = (uint32_t)__shfl_up((int)sc, d);
            if (lane >= d) sc += t;
        }
        if (lane == 63) swred[wid] = sc;
        __syncthreads();                                   // S3
#pragma unroll
        for (int w = 0; w < 4; ++w)
            if (w < wid) sc += swred[w];
        // sc = count of candidate digits >= b. Unique bin satisfies:
        if (sc >= rk && (sc - x) < rk) {
            s_sel[0] = b;
            s_sel[1] = rk - (sc - x);   // still-needed among digit==b
        }
        __syncthreads();                                   // S4
        const uint32_t dsel = s_sel[0];
        rk = s_sel[1];
        prefix = (prefix << 8) | dsel;
#pragma unroll
        for (int j = 0; j < 8; ++j)
            if (((u[j] >> shift) & 255u) != dsel) cand &= ~(1u << j);
    }
    const uint32_t T = prefix;          // k-th largest value (exact)
    const float eT = __expf(u2f(T) - M);

    // ---- sum of kept exps + count of equals ----
    float sp = 0.f;
    uint32_t ceq = 0;
#pragma unroll
    for (int j = 0; j < 8; ++j) {
        if (u[j] > T) sp += e[j];
        ceq += (u[j] == T) ? 1u : 0u;
    }
#pragma unroll
    for (int d = 32; d > 0; d >>= 1) {
        sp  += __shfl_xor(sp, d);
        ceq += (uint32_t)__shfl_xor((int)ceq, d);
    }
    __syncthreads();                    // free swred/sfred for reuse
    if (lane == 0) { sfred[wid] = sp; swred[wid] = ceq; }
    __syncthreads();
    float S = (sfred[0] + sfred[1]) + (sfred[2] + sfred[3]);
    ceq = swred[0] + swred[1] + swred[2] + swred[3];
    S += (float)rk * eT;                // rk equal-to-T elements are kept
    const float inv = 1.0f / S;
    const bool need_rank = (ceq > rk);  // true boundary tie: almost never

    // ---- write full row (masked-out positions are exactly 0.0f) ----
    float o[8];
#pragma unroll
    for (int j = 0; j < 8; ++j) {
        float val = 0.f;
        if (u[j] > T) {
            val = e[j] * inv;
        } else if (u[j] == T) {
            if (!need_rank) {
                val = e[j] * inv;
            } else {
                // lax.top_k tie-break: lower index wins. Rank among equals by index.
                const int idx = (j < 4) ? (base0 + j) : (base1 + (j - 4));
                int rank = 0;
                for (int i = 0; i < idx; ++i) rank += (su[i] == T) ? 1 : 0;
                if (rank < (int)rk) val = e[j] * inv;
            }
        }
        o[j] = val;
    }
    float4 o0 = {o[0], o[1], o[2], o[3]};
    float4 o1 = {o[4], o[5], o[6], o[7]};
    dst4[tid]       = o0;
    dst4[tid + NTH] = o1;
}

extern "C" void kernel_launch(void* const* d_in, const int* in_sizes, int n_in,
                              void* d_out, int out_size, void* d_ws, size_t ws_size,
                              hipStream_t stream) {
    const float* in = (const float*)d_in[0];
    float* out = (float*)d_out;
    const int rows = in_sizes[0] / ROWN;   // 8*4*2048 = 65536
    hipLaunchKernelGGL(topk_softmax_kernel, dim3(rows), dim3(NTH), 0, stream,
                       in, out);
}